// Round 11
// baseline (358.808 us; speedup 1.0000x reference)
//
#include <hip/hip_runtime.h>
#include <math.h>

#define DD 128
#define NNODES 100000
#define NEDGES 600000
#define NREL 3
#define MTOT (NREL*NNODES)
#define NTILES (NNODES/16)          // 6250 row-tiles per relation
#define RT_PER_BLK 8                // 128 rows per block
#define NBLK_REL ((NTILES + RT_PER_BLK - 1)/RT_PER_BLK)   // 782
#define ATT_WAVES 8

// bucketed CSR build (256-node buckets end-to-end)
#define BSHIFT 8
#define NBUCK ((NNODES + 255) >> BSHIFT)    // 391 buckets of 256 nodes
#define GBUCK (NREL*NBUCK)                  // 1173
#define CAP 2048                            // mean 1534, sigma 39 -> +13 sigma
#define P1_THREADS 512
#define P1_EPT 8
#define P1_EPB (P1_THREADS*P1_EPT)          // 4096 edges/block
#define P1_BLOCKS ((NREL*NEDGES + P1_EPB - 1)/P1_EPB)   // 440

// fused front-end block ranges: [part | transform | w1-cvt]
#define TR_BLOCKS ((NTILES + 7)/8)          // 782 (8 row-tiles per 512-thr block)
#define CVT_BLOCKS ((512*DD/4 + 511)/512)   // 32
#define FRONT_BLOCKS (P1_BLOCKS + TR_BLOCKS + CVT_BLOCKS)   // 1254

typedef __attribute__((ext_vector_type(8))) short short8;
typedef __attribute__((ext_vector_type(4))) float f32x4;

__device__ inline float bf2f(unsigned short u){ return __uint_as_float(((unsigned int)u)<<16); }
__device__ inline float bflo(unsigned int u){ return __uint_as_float(u<<16); }
__device__ inline float bfhi(unsigned int u){ return __uint_as_float(u & 0xffff0000u); }
__device__ inline unsigned short f2bf(float f){          // RNE fp32->bf16
    unsigned int i = __float_as_uint(f);
    unsigned int r = (i + 0x7fffu + ((i>>16)&1u)) >> 16;
    return (unsigned short)r;
}
__device__ inline unsigned int pack2(float lo, float hi){
    return (unsigned int)f2bf(lo) | ((unsigned int)f2bf(hi) << 16);
}
__device__ inline short8 cvt8(const float* __restrict__ p){  // 8 fp32 -> bf16x8
    f32x4 a = *(const f32x4*)p;
    f32x4 b = *(const f32x4*)(p+4);
    short8 t;
    t[0]=(short)f2bf(a[0]); t[1]=(short)f2bf(a[1]); t[2]=(short)f2bf(a[2]); t[3]=(short)f2bf(a[3]);
    t[4]=(short)f2bf(b[0]); t[5]=(short)f2bf(b[1]); t[6]=(short)f2bf(b[2]); t[7]=(short)f2bf(b[3]);
    return t;
}
__device__ inline void acc8(float* a, float w, uint4 v){
    a[0] += w*bflo(v.x); a[1] += w*bfhi(v.x);
    a[2] += w*bflo(v.y); a[3] += w*bfhi(v.y);
    a[4] += w*bflo(v.z); a[5] += w*bfhi(v.z);
    a[6] += w*bflo(v.w); a[7] += w*bfhi(v.w);
}

// ---- K_FRONT: fused independent front-end ------------------------------------
// Role by block range:
//   [0, P1_BLOCKS)        edge partition into (rel, 256-node-range) buckets
//   [.., +TR_BLOCKS)      f = feat @ W^T (W converted to bf16 in LDS once/block)
//   [.., +CVT_BLOCKS)     att_w1 fp32 -> bf16
// LDS: 32 KB buffer unioned across roles (hist | W-tile).
__global__ __launch_bounds__(512) void k_front(
    const float* __restrict__ feat, const float* __restrict__ W,
    const float* __restrict__ aw1,
    const int* __restrict__ s0, const int* __restrict__ d0,
    const int* __restrict__ s1, const int* __restrict__ d1,
    const int* __restrict__ s2, const int* __restrict__ d2,
    const float* __restrict__ tw,
    int* __restrict__ bcur, int2* __restrict__ slab, float* __restrict__ wslab,
    unsigned short* __restrict__ w1_bf, unsigned short* __restrict__ f_out)
{
    __shared__ char smraw[32768];
    int bid = blockIdx.x;

    if (bid < P1_BLOCKS){
        // ---------------- partition role ----------------
        int* hist = (int*)smraw;             // GBUCK=1173 ints = 4.7 KB
        for (int i=threadIdx.x; i<GBUCK; i+=512) hist[i]=0;
        __syncthreads();

        int e0 = bid * P1_EPB;
        int ss[P1_EPT], dd_[P1_EPT], gb[P1_EPT]; float wv[P1_EPT];
        #pragma unroll
        for (int j=0;j<P1_EPT;++j){
            int e = e0 + j*512 + threadIdx.x;
            gb[j] = -1;
            if (e < NREL*NEDGES){
                int rel = e / NEDGES; int i = e - rel*NEDGES;
                const int* s = (rel==0)?s0:(rel==1)?s1:s2;
                const int* d = (rel==0)?d0:(rel==1)?d1:d2;
                ss[j]=s[i]; dd_[j]=d[i];
                wv[j] = (rel==2)? tw[i] : 0.f;
                gb[j] = rel*NBUCK + (dd_[j]>>BSHIFT);
                atomicAdd(&hist[gb[j]], 1);
            }
        }
        __syncthreads();
        for (int i=threadIdx.x; i<GBUCK; i+=512){
            int c = hist[i];
            hist[i] = (c>0) ? atomicAdd(&bcur[i], c) : 0;   // count -> block base
        }
        __syncthreads();
        #pragma unroll
        for (int j=0;j<P1_EPT;++j){
            if (gb[j] >= 0){
                int off = atomicAdd(&hist[gb[j]], 1);
                int2 pr; pr.x = ss[j]; pr.y = dd_[j];
                slab[(size_t)gb[j]*CAP + off] = pr;
                if (gb[j] >= 2*NBUCK) wslab[(size_t)(gb[j]-2*NBUCK)*CAP + off] = wv[j];
            }
        }
    } else if (bid < P1_BLOCKS + TR_BLOCKS){
        // ---------------- transform role (8 row-tiles/block) ----------------
        short8* wlds = (short8*)smraw;       // bf16 [128][16 chunks], chunk^=(row&7)
        {
            int t = threadIdx.x;             // thread t: row t>>2, chunks (t&3)*4..+4
            int row = t >> 2;
            int c0  = (t & 3) * 4;
            const float* wrow = W + (size_t)row*DD;
            #pragma unroll
            for (int cc=0; cc<4; ++cc){
                int chunk = c0 + cc;
                wlds[row*16 + (chunk ^ (row & 7))] = cvt8(wrow + chunk*8);
            }
        }
        __syncthreads();

        int wid = (bid - P1_BLOCKS)*8 + (threadIdx.x>>6);
        if (wid >= NTILES) return;
        int lane = threadIdx.x & 63;
        int m = lane & 15, quad = lane >> 4;
        int n0 = wid*16;

        short8 a[4];                                   // A[m][k], k=ks*32+quad*8+j
        const float* arow = feat + (size_t)(n0+m)*DD;
        #pragma unroll
        for (int ks=0; ks<4; ++ks) a[ks] = cvt8(arow + ks*32 + quad*8);

        #pragma unroll
        for (int ct=0; ct<8; ++ct){
            f32x4 acc = {0.f,0.f,0.f,0.f};
            int brow = ct*16 + m;                      // B[k][n]=W[n][k]
            #pragma unroll
            for (int ks=0; ks<4; ++ks){
                short8 b = wlds[brow*16 + ((ks*4 + quad) ^ (brow & 7))];
                acc = __builtin_amdgcn_mfma_f32_16x16x32_bf16(a[ks], b, acc, 0,0,0);
            }
            int col = ct*16 + m;
            #pragma unroll
            for (int i=0;i<4;++i)                      // C/D: col=lane&15, row=quad*4+reg
                f_out[(size_t)(n0+quad*4+i)*DD + col] = f2bf(acc[i]);
        }
    } else {
        // ---------------- w1 conversion role ----------------
        int gid = (bid - P1_BLOCKS - TR_BLOCKS)*512 + threadIdx.x;
        if (gid < 512*DD/4){
            f32x4 v = ((const f32x4*)aw1)[gid];
            ushort4 o;
            o.x=f2bf(v[0]); o.y=f2bf(v[1]); o.z=f2bf(v[2]); o.w=f2bf(v[3]);
            ((ushort4*)w1_bf)[gid] = o;
        }
    }
}

// ---- K_CSRAGG: per-bucket CSR (fully in LDS) + aggregation -------------------
// One block per (rel, 256-node bucket). Every slab edge belongs to this block
// (no half-bucket filtering/double-read). Hist+scan+scatter build the node
// edge lists in LDS; agg phase: 32 groups x 16 lanes, 4-deep gather unroll.
__global__ __launch_bounds__(512) void k_csragg(
    const int2* __restrict__ slab, const float* __restrict__ wslab,
    const int* __restrict__ bcur,
    const unsigned short* __restrict__ f,   // bf16 [N,128]
    unsigned short* __restrict__ z)         // bf16 [3,N,128]
{
    __shared__ int lcnt[256];
    __shared__ int lsc[256];
    __shared__ int psum[256];
    __shared__ int es_l[CAP];
    __shared__ float ewt_l[CAP];

    int gb = blockIdx.x;
    int rel = gb / NBUCK, b = gb - rel*NBUCK;
    int n0 = b << BSHIFT;
    int nn = min(256, NNODES - n0);
    int ecount = bcur[gb];
    const int2* ep = slab + (size_t)gb*CAP;
    int t = threadIdx.x;
    bool wr = (rel == 2);

    if (t < 256) lcnt[t] = 0;
    __syncthreads();
    for (int i=t; i<ecount; i+=512)
        atomicAdd(&lcnt[ep[i].y - n0], 1);
    __syncthreads();
    int v = 0;
    if (t < 256){ v = lcnt[t]; psum[t] = v; }
    __syncthreads();
    for (int off=1; off<256; off<<=1){
        int x = 0;
        if (t < 256 && t >= off) x = psum[t-off];
        __syncthreads();
        if (t < 256) psum[t] += x;
        __syncthreads();
    }
    if (t < 256) lsc[t] = psum[t] - v;      // exclusive start
    __syncthreads();
    for (int i=t; i<ecount; i+=512){
        int2 pr = ep[i];
        int pos = atomicAdd(&lsc[pr.y - n0], 1);
        es_l[pos] = pr.x;
        if (wr) ewt_l[pos] = wslab[(size_t)b*CAP + i];
    }
    __syncthreads();                         // lsc[n] now = END offset

    int grp = t >> 4, c = t & 15;
    for (int pass=0; pass<8; ++pass){
        int n = pass*32 + grp;               // 0..255
        if (n >= nn) break;                  // monotone in pass -> safe
        int deg = lcnt[n];
        int start = lsc[n] - deg;
        float a[8] = {0,0,0,0,0,0,0,0};
        int i = 0;
        if (!wr){
            for (; i+3 < deg; i += 4){
                int s0 = es_l[start+i],   s1 = es_l[start+i+1];
                int s2 = es_l[start+i+2], s3 = es_l[start+i+3];
                uint4 v0 = *(const uint4*)(f + (size_t)s0*DD + c*8);
                uint4 v1 = *(const uint4*)(f + (size_t)s1*DD + c*8);
                uint4 v2 = *(const uint4*)(f + (size_t)s2*DD + c*8);
                uint4 v3 = *(const uint4*)(f + (size_t)s3*DD + c*8);
                acc8(a,1.f,v0); acc8(a,1.f,v1); acc8(a,1.f,v2); acc8(a,1.f,v3);
            }
            if (i+1 < deg){
                int s0 = es_l[start+i], s1 = es_l[start+i+1];
                uint4 v0 = *(const uint4*)(f + (size_t)s0*DD + c*8);
                uint4 v1 = *(const uint4*)(f + (size_t)s1*DD + c*8);
                acc8(a,1.f,v0); acc8(a,1.f,v1);
                i += 2;
            }
            if (i < deg){
                int s = es_l[start+i];
                uint4 vv = *(const uint4*)(f + (size_t)s*DD + c*8);
                acc8(a,1.f,vv);
            }
            float sc = 1.f/fmaxf((float)deg, 1.f);
            #pragma unroll
            for (int k=0;k<8;++k) a[k] *= sc;
        } else {
            for (; i+3 < deg; i += 4){
                int s0 = es_l[start+i],   s1 = es_l[start+i+1];
                int s2 = es_l[start+i+2], s3 = es_l[start+i+3];
                float w0 = ewt_l[start+i],   w1 = ewt_l[start+i+1];
                float w2 = ewt_l[start+i+2], w3 = ewt_l[start+i+3];
                uint4 v0 = *(const uint4*)(f + (size_t)s0*DD + c*8);
                uint4 v1 = *(const uint4*)(f + (size_t)s1*DD + c*8);
                uint4 v2 = *(const uint4*)(f + (size_t)s2*DD + c*8);
                uint4 v3 = *(const uint4*)(f + (size_t)s3*DD + c*8);
                acc8(a,w0,v0); acc8(a,w1,v1); acc8(a,w2,v2); acc8(a,w3,v3);
            }
            if (i+1 < deg){
                int s0 = es_l[start+i], s1 = es_l[start+i+1];
                float w0 = ewt_l[start+i], w1 = ewt_l[start+i+1];
                uint4 v0 = *(const uint4*)(f + (size_t)s0*DD + c*8);
                uint4 v1 = *(const uint4*)(f + (size_t)s1*DD + c*8);
                acc8(a,w0,v0); acc8(a,w1,v1);
                i += 2;
            }
            if (i < deg){
                int s = es_l[start+i];
                float w = ewt_l[start+i];
                uint4 vv = *(const uint4*)(f + (size_t)s*DD + c*8);
                acc8(a,w,vv);
            }
        }
        uint4 o;
        o.x = pack2(a[0], a[1]);
        o.y = pack2(a[2], a[3]);
        o.z = pack2(a[4], a[5]);
        o.w = pack2(a[6], a[7]);
        *(uint4*)(z + (size_t)(rel*NNODES + n0 + n)*DD + c*8) = o;
    }
}

// ---- K4: w_part = sum_n w2 . tanh(W1 z_n + b1) -------------------------------
// v2: BARRIER-FREE per wave. No LDS staging — each wave loads its A-frags
// directly from global z (L2/L3-hot, written by csragg). Removes the
// stage/compute phase convoy; waves drift and interleave mem+compute.
// rt loop 2-stage pipelined (global latency under MFMA+tanh).
// w_part spread over 8 slots/rel.
__global__ __launch_bounds__(512, 4) void k_att(
    const unsigned short* __restrict__ z,    // bf16 [3,N,128]
    const unsigned short* __restrict__ w1,   // bf16 [512,128]
    const float* __restrict__ bias1,         // fp32 [512]
    const float* __restrict__ wv2,           // fp32 [512]
    float* __restrict__ w_part)              // fp32 [3*8] slots
{
    __shared__ float sred[ATT_WAVES];
    const float C2 = 2.8853900817779268f;    // 2*log2(e)

    int rel = blockIdx.x / NBLK_REL;
    int nb  = blockIdx.x % NBLK_REL;
    int trt0 = nb * RT_PER_BLK;
    int rt_count = min(RT_PER_BLK, NTILES - trt0);
    int row0 = trt0 * 16;
    const unsigned short* zrel = z + (size_t)rel*NNODES*DD;

    int lane = threadIdx.x & 63;
    int wv   = threadIdx.x >> 6;             // wave 0..7 -> cols [wv*64, wv*64+64)
    int m = lane & 15, quad = lane >> 4;

    // B fragments in registers: 4 col-tiles x 4 k-slices
    short8 bq[16];
    float ww[4], bbc[4];
    #pragma unroll
    for (int ct=0; ct<4; ++ct){
        int col = (wv*4 + ct)*16 + m;
        const short8* brow = (const short8*)(w1 + (size_t)col*DD);
        #pragma unroll
        for (int ks=0; ks<4; ++ks) bq[ct*4+ks] = brow[ks*4 + quad];
        ww[ct]  = wv2[col];
        bbc[ct] = bias1[col] * C2;
    }

    // per-wave A-frag base: row (row0 + rt*16 + m), col chunk quad*8 (+ks*32)
    const unsigned short* rp = zrel + (size_t)(row0 + m)*DD + quad*8;

    float s_r[4] = {0.f,0.f,0.f,0.f};
    short8 a0 = *(const short8*)(rp);
    short8 a1 = *(const short8*)(rp + 32);
    short8 a2 = *(const short8*)(rp + 64);
    short8 a3 = *(const short8*)(rp + 96);
    for (int rt=0; rt<rt_count; ++rt){
        short8 n0_, n1_, n2_, n3_;
        if (rt+1 < rt_count){                // prefetch next row-tile's A-frags
            const unsigned short* np = rp + (size_t)(rt+1)*16*DD;
            n0_ = *(const short8*)(np);
            n1_ = *(const short8*)(np + 32);
            n2_ = *(const short8*)(np + 64);
            n3_ = *(const short8*)(np + 96);
        } else { n0_ = a0; n1_ = a1; n2_ = a2; n3_ = a3; }
        #pragma unroll
        for (int ct=0; ct<4; ++ct){
            f32x4 acc = {0.f,0.f,0.f,0.f};
            acc = __builtin_amdgcn_mfma_f32_16x16x32_bf16(a0, bq[ct*4+0], acc, 0,0,0);
            acc = __builtin_amdgcn_mfma_f32_16x16x32_bf16(a1, bq[ct*4+1], acc, 0,0,0);
            acc = __builtin_amdgcn_mfma_f32_16x16x32_bf16(a2, bq[ct*4+2], acc, 0,0,0);
            acc = __builtin_amdgcn_mfma_f32_16x16x32_bf16(a3, bq[ct*4+3], acc, 0,0,0);
            #pragma unroll
            for (int i=0;i<4;++i){
                float e = __builtin_amdgcn_exp2f(__builtin_fmaf(acc[i], C2, bbc[ct]));
                s_r[ct] += __builtin_amdgcn_rcpf(e + 1.f);
            }
        }
        a0 = n0_; a1 = n1_; a2 = n2_; a3 = n3_;
    }
    float s_all = 0.f;
    #pragma unroll
    for (int ct=0; ct<4; ++ct)
        s_all += ww[ct]*(float)(4*rt_count) - 2.f*ww[ct]*s_r[ct];
    #pragma unroll
    for (int off=32; off; off>>=1) s_all += __shfl_xor(s_all, off);
    if (lane == 0) sred[wv] = s_all;
    __syncthreads();
    if (threadIdx.x == 0){
        float tt = 0.f;
        #pragma unroll
        for (int i=0;i<ATT_WAVES;++i) tt += sred[i];
        atomicAdd(&w_part[rel*8 + (nb & 7)], tt);    // 8 slots/rel
    }
}

// ---- K5: softmax(3) + fuse + leaky relu, fp32 out ----------------------------
__global__ __launch_bounds__(256) void k_final(
    const unsigned short* __restrict__ z0, const unsigned short* __restrict__ z1,
    const unsigned short* __restrict__ z2,
    const float* __restrict__ w_part, float* __restrict__ out)
{
    int gid = blockIdx.x*256 + threadIdx.x;      // one per 4 elements
    if (gid >= NNODES*DD/4) return;
    const float invN = 1.f / (float)NNODES;
    float w0=0.f, w1=0.f, w2=0.f;
    #pragma unroll
    for (int i=0;i<8;++i){ w0 += w_part[i]; w1 += w_part[8+i]; w2 += w_part[16+i]; }
    w0 *= invN; w1 *= invN; w2 *= invN;
    float mx = fmaxf(w0, fmaxf(w1, w2));
    const float LOG2E = 1.4426950408889634f;
    float e0 = __builtin_amdgcn_exp2f((w0-mx)*LOG2E);
    float e1 = __builtin_amdgcn_exp2f((w1-mx)*LOG2E);
    float e2 = __builtin_amdgcn_exp2f((w2-mx)*LOG2E);
    float inv = 1.f/(e0+e1+e2);
    float b0 = e0*inv, b1 = e1*inv, b2 = e2*inv;
    ushort4 g = ((const ushort4*)z0)[gid];
    ushort4 t = ((const ushort4*)z1)[gid];
    ushort4 c = ((const ushort4*)z2)[gid];
    f32x4 o;
    float gv[4] = {bf2f(g.x),bf2f(g.y),bf2f(g.z),bf2f(g.w)};
    float tv[4] = {bf2f(t.x),bf2f(t.y),bf2f(t.z),bf2f(t.w)};
    float cv[4] = {bf2f(c.x),bf2f(c.y),bf2f(c.z),bf2f(c.w)};
    #pragma unroll
    for (int i=0;i<4;++i){
        float x = b0*gv[i] + b1*tv[i] + b2*cv[i];
        o[i] = (x > 0.f) ? x : 0.2f*x;
    }
    ((f32x4*)out)[gid] = o;
}

extern "C" void kernel_launch(void* const* d_in, const int* in_sizes, int n_in,
                              void* d_out, int out_size, void* d_ws, size_t ws_size,
                              hipStream_t stream)
{
    const float* feat = (const float*)d_in[0];
    const float* W    = (const float*)d_in[1];
    const float* aw1  = (const float*)d_in[2];
    const float* ab1  = (const float*)d_in[3];
    const float* aw2  = (const float*)d_in[4];
    const float* tw   = (const float*)d_in[5];
    const int* geo_src   = (const int*)d_in[6];
    const int* geo_dst   = (const int*)d_in[7];
    const int* cat_src   = (const int*)d_in[8];
    const int* cat_dst   = (const int*)d_in[9];
    const int* trans_src = (const int*)d_in[10];
    const int* trans_dst = (const int*)d_in[11];

    // ws layout (~77 MB): w_part | bcur | w1_bf | z
    // slab/wslab (22.4 MB) live in the UPPER HALF of d_out (f_bf uses the lower
    // 25.6 MB); both are dead by the time k_final overwrites d_out.
    char* ws = (char*)d_ws;
    float* w_part = (float*)ws;                      // [64] (24 used)
    int*   bcur   = (int*)(w_part + 64);             // [1280] (GBUCK=1173, padded)
    unsigned short* w1_bf = (unsigned short*)(bcur + 1280);      // [512*128]
    unsigned short* z = w1_bf + 512*DD;              // [3N*128] geo|cat|trans

    unsigned short* f_bf = (unsigned short*)d_out;   // [N*128] bf16 (lower half)
    int2*  slab  = (int2*)((char*)d_out + (size_t)NNODES*DD*sizeof(unsigned short));
    float* wslab = (float*)(slab + (size_t)GBUCK*CAP);

    // zero w_part + bcur (contiguous)
    (void)hipMemsetAsync(w_part, 0, (64 + 1280)*sizeof(int), stream);

    k_front<<<FRONT_BLOCKS, 512, 0, stream>>>(feat, W, aw1,
                                              geo_src, geo_dst, cat_src, cat_dst,
                                              trans_src, trans_dst, tw,
                                              bcur, slab, wslab, w1_bf, f_bf);

    k_csragg<<<GBUCK, 512, 0, stream>>>(slab, wslab, bcur, f_bf, z);

    // k_att over memory-relation order (0=geo, 1=cat, 2=trans)
    k_att<<<NREL*NBLK_REL, 512, 0, stream>>>(z, w1_bf, ab1, aw2, w_part);

    unsigned short* z_geo   = z;
    unsigned short* z_cat   = z + (size_t)NNODES*DD;
    unsigned short* z_trans = z + (size_t)2*NNODES*DD;
    int dg = (NNODES*DD/4 + 255)/256;
    k_final<<<dg, 256, 0, stream>>>(z_geo, z_cat, z_trans, w_part, (float*)d_out);
}

// Round 12
// 319.536 us; speedup vs baseline: 1.1229x; 1.1229x over previous
//
#include <hip/hip_runtime.h>
#include <math.h>

#define DD 128
#define NNODES 100000
#define NEDGES 600000
#define NREL 3
#define MTOT (NREL*NNODES)
#define NTILES (NNODES/16)          // 6250 row-tiles per relation
#define RT_PER_BLK 8                // 128 rows per block
#define NBLK_REL ((NTILES + RT_PER_BLK - 1)/RT_PER_BLK)   // 782
#define ATT_WAVES 8

// bucketed CSR build (256-node buckets end-to-end)
#define BSHIFT 8
#define NBUCK ((NNODES + 255) >> BSHIFT)    // 391 buckets of 256 nodes
#define GBUCK (NREL*NBUCK)                  // 1173
#define CAP 2048                            // mean 1534, sigma 39 -> +13 sigma
#define P1_THREADS 512
#define P1_EPT 8
#define P1_EPB (P1_THREADS*P1_EPT)          // 4096 edges/block
#define P1_BLOCKS ((NREL*NEDGES + P1_EPB - 1)/P1_EPB)   // 440

// fused front-end block ranges: [part | transform | w1-cvt]
#define TR_BLOCKS ((NTILES + 7)/8)          // 782 (8 row-tiles per 512-thr block)
#define CVT_BLOCKS ((512*DD/4 + 511)/512)   // 32
#define FRONT_BLOCKS (P1_BLOCKS + TR_BLOCKS + CVT_BLOCKS)   // 1254

typedef __attribute__((ext_vector_type(8))) short short8;
typedef __attribute__((ext_vector_type(4))) float f32x4;

__device__ inline float bf2f(unsigned short u){ return __uint_as_float(((unsigned int)u)<<16); }
__device__ inline float bflo(unsigned int u){ return __uint_as_float(u<<16); }
__device__ inline float bfhi(unsigned int u){ return __uint_as_float(u & 0xffff0000u); }
__device__ inline unsigned short f2bf(float f){          // RNE fp32->bf16
    unsigned int i = __float_as_uint(f);
    unsigned int r = (i + 0x7fffu + ((i>>16)&1u)) >> 16;
    return (unsigned short)r;
}
__device__ inline unsigned int pack2(float lo, float hi){
    return (unsigned int)f2bf(lo) | ((unsigned int)f2bf(hi) << 16);
}
__device__ inline short8 cvt8(const float* __restrict__ p){  // 8 fp32 -> bf16x8
    f32x4 a = *(const f32x4*)p;
    f32x4 b = *(const f32x4*)(p+4);
    short8 t;
    t[0]=(short)f2bf(a[0]); t[1]=(short)f2bf(a[1]); t[2]=(short)f2bf(a[2]); t[3]=(short)f2bf(a[3]);
    t[4]=(short)f2bf(b[0]); t[5]=(short)f2bf(b[1]); t[6]=(short)f2bf(b[2]); t[7]=(short)f2bf(b[3]);
    return t;
}
__device__ inline void acc8(float* a, float w, uint4 v){
    a[0] += w*bflo(v.x); a[1] += w*bfhi(v.x);
    a[2] += w*bflo(v.y); a[3] += w*bfhi(v.y);
    a[4] += w*bflo(v.z); a[5] += w*bfhi(v.z);
    a[6] += w*bflo(v.w); a[7] += w*bfhi(v.w);
}

// ---- K_FRONT: fused independent front-end ------------------------------------
// Role by block range:
//   [0, P1_BLOCKS)        edge partition into (rel, 256-node-range) buckets
//   [.., +TR_BLOCKS)      f = feat @ W^T (W converted to bf16 in LDS once/block)
//   [.., +CVT_BLOCKS)     att_w1 fp32 -> bf16
// LDS: 32 KB buffer unioned across roles (hist | W-tile).
__global__ __launch_bounds__(512) void k_front(
    const float* __restrict__ feat, const float* __restrict__ W,
    const float* __restrict__ aw1,
    const int* __restrict__ s0, const int* __restrict__ d0,
    const int* __restrict__ s1, const int* __restrict__ d1,
    const int* __restrict__ s2, const int* __restrict__ d2,
    const float* __restrict__ tw,
    int* __restrict__ bcur, int2* __restrict__ slab, float* __restrict__ wslab,
    unsigned short* __restrict__ w1_bf, unsigned short* __restrict__ f_out)
{
    __shared__ char smraw[32768];
    int bid = blockIdx.x;

    if (bid < P1_BLOCKS){
        // ---------------- partition role ----------------
        int* hist = (int*)smraw;             // GBUCK=1173 ints = 4.7 KB
        for (int i=threadIdx.x; i<GBUCK; i+=512) hist[i]=0;
        __syncthreads();

        int e0 = bid * P1_EPB;
        int ss[P1_EPT], dd_[P1_EPT], gb[P1_EPT]; float wv[P1_EPT];
        #pragma unroll
        for (int j=0;j<P1_EPT;++j){
            int e = e0 + j*512 + threadIdx.x;
            gb[j] = -1;
            if (e < NREL*NEDGES){
                int rel = e / NEDGES; int i = e - rel*NEDGES;
                const int* s = (rel==0)?s0:(rel==1)?s1:s2;
                const int* d = (rel==0)?d0:(rel==1)?d1:d2;
                ss[j]=s[i]; dd_[j]=d[i];
                wv[j] = (rel==2)? tw[i] : 0.f;
                gb[j] = rel*NBUCK + (dd_[j]>>BSHIFT);
                atomicAdd(&hist[gb[j]], 1);
            }
        }
        __syncthreads();
        for (int i=threadIdx.x; i<GBUCK; i+=512){
            int c = hist[i];
            hist[i] = (c>0) ? atomicAdd(&bcur[i], c) : 0;   // count -> block base
        }
        __syncthreads();
        #pragma unroll
        for (int j=0;j<P1_EPT;++j){
            if (gb[j] >= 0){
                int off = atomicAdd(&hist[gb[j]], 1);
                int2 pr; pr.x = ss[j]; pr.y = dd_[j];
                slab[(size_t)gb[j]*CAP + off] = pr;
                if (gb[j] >= 2*NBUCK) wslab[(size_t)(gb[j]-2*NBUCK)*CAP + off] = wv[j];
            }
        }
    } else if (bid < P1_BLOCKS + TR_BLOCKS){
        // ---------------- transform role (8 row-tiles/block) ----------------
        short8* wlds = (short8*)smraw;       // bf16 [128][16 chunks], chunk^=(row&7)
        {
            int t = threadIdx.x;             // thread t: row t>>2, chunks (t&3)*4..+4
            int row = t >> 2;
            int c0  = (t & 3) * 4;
            const float* wrow = W + (size_t)row*DD;
            #pragma unroll
            for (int cc=0; cc<4; ++cc){
                int chunk = c0 + cc;
                wlds[row*16 + (chunk ^ (row & 7))] = cvt8(wrow + chunk*8);
            }
        }
        __syncthreads();

        int wid = (bid - P1_BLOCKS)*8 + (threadIdx.x>>6);
        if (wid >= NTILES) return;
        int lane = threadIdx.x & 63;
        int m = lane & 15, quad = lane >> 4;
        int n0 = wid*16;

        short8 a[4];                                   // A[m][k], k=ks*32+quad*8+j
        const float* arow = feat + (size_t)(n0+m)*DD;
        #pragma unroll
        for (int ks=0; ks<4; ++ks) a[ks] = cvt8(arow + ks*32 + quad*8);

        #pragma unroll
        for (int ct=0; ct<8; ++ct){
            f32x4 acc = {0.f,0.f,0.f,0.f};
            int brow = ct*16 + m;                      // B[k][n]=W[n][k]
            #pragma unroll
            for (int ks=0; ks<4; ++ks){
                short8 b = wlds[brow*16 + ((ks*4 + quad) ^ (brow & 7))];
                acc = __builtin_amdgcn_mfma_f32_16x16x32_bf16(a[ks], b, acc, 0,0,0);
            }
            int col = ct*16 + m;
            #pragma unroll
            for (int i=0;i<4;++i)                      // C/D: col=lane&15, row=quad*4+reg
                f_out[(size_t)(n0+quad*4+i)*DD + col] = f2bf(acc[i]);
        }
    } else {
        // ---------------- w1 conversion role ----------------
        int gid = (bid - P1_BLOCKS - TR_BLOCKS)*512 + threadIdx.x;
        if (gid < 512*DD/4){
            f32x4 v = ((const f32x4*)aw1)[gid];
            ushort4 o;
            o.x=f2bf(v[0]); o.y=f2bf(v[1]); o.z=f2bf(v[2]); o.w=f2bf(v[3]);
            ((ushort4*)w1_bf)[gid] = o;
        }
    }
}

// ---- K_CSRAGG: per-bucket CSR (fully in LDS) + aggregation -------------------
// One block per (rel, 256-node bucket). Every slab edge belongs to this block
// (no half-bucket filtering/double-read). Hist+scan+scatter build the node
// edge lists in LDS; agg phase: 32 groups x 16 lanes, 4-deep gather unroll.
__global__ __launch_bounds__(512) void k_csragg(
    const int2* __restrict__ slab, const float* __restrict__ wslab,
    const int* __restrict__ bcur,
    const unsigned short* __restrict__ f,   // bf16 [N,128]
    unsigned short* __restrict__ z)         // bf16 [3,N,128]
{
    __shared__ int lcnt[256];
    __shared__ int lsc[256];
    __shared__ int psum[256];
    __shared__ int es_l[CAP];
    __shared__ float ewt_l[CAP];

    int gb = blockIdx.x;
    int rel = gb / NBUCK, b = gb - rel*NBUCK;
    int n0 = b << BSHIFT;
    int nn = min(256, NNODES - n0);
    int ecount = bcur[gb];
    const int2* ep = slab + (size_t)gb*CAP;
    int t = threadIdx.x;
    bool wr = (rel == 2);

    if (t < 256) lcnt[t] = 0;
    __syncthreads();
    for (int i=t; i<ecount; i+=512)
        atomicAdd(&lcnt[ep[i].y - n0], 1);
    __syncthreads();
    int v = 0;
    if (t < 256){ v = lcnt[t]; psum[t] = v; }
    __syncthreads();
    for (int off=1; off<256; off<<=1){
        int x = 0;
        if (t < 256 && t >= off) x = psum[t-off];
        __syncthreads();
        if (t < 256) psum[t] += x;
        __syncthreads();
    }
    if (t < 256) lsc[t] = psum[t] - v;      // exclusive start
    __syncthreads();
    for (int i=t; i<ecount; i+=512){
        int2 pr = ep[i];
        int pos = atomicAdd(&lsc[pr.y - n0], 1);
        es_l[pos] = pr.x;
        if (wr) ewt_l[pos] = wslab[(size_t)b*CAP + i];
    }
    __syncthreads();                         // lsc[n] now = END offset

    int grp = t >> 4, c = t & 15;
    for (int pass=0; pass<8; ++pass){
        int n = pass*32 + grp;               // 0..255
        if (n >= nn) break;                  // monotone in pass -> safe
        int deg = lcnt[n];
        int start = lsc[n] - deg;
        float a[8] = {0,0,0,0,0,0,0,0};
        int i = 0;
        if (!wr){
            for (; i+3 < deg; i += 4){
                int s0 = es_l[start+i],   s1 = es_l[start+i+1];
                int s2 = es_l[start+i+2], s3 = es_l[start+i+3];
                uint4 v0 = *(const uint4*)(f + (size_t)s0*DD + c*8);
                uint4 v1 = *(const uint4*)(f + (size_t)s1*DD + c*8);
                uint4 v2 = *(const uint4*)(f + (size_t)s2*DD + c*8);
                uint4 v3 = *(const uint4*)(f + (size_t)s3*DD + c*8);
                acc8(a,1.f,v0); acc8(a,1.f,v1); acc8(a,1.f,v2); acc8(a,1.f,v3);
            }
            if (i+1 < deg){
                int s0 = es_l[start+i], s1 = es_l[start+i+1];
                uint4 v0 = *(const uint4*)(f + (size_t)s0*DD + c*8);
                uint4 v1 = *(const uint4*)(f + (size_t)s1*DD + c*8);
                acc8(a,1.f,v0); acc8(a,1.f,v1);
                i += 2;
            }
            if (i < deg){
                int s = es_l[start+i];
                uint4 vv = *(const uint4*)(f + (size_t)s*DD + c*8);
                acc8(a,1.f,vv);
            }
            float sc = 1.f/fmaxf((float)deg, 1.f);
            #pragma unroll
            for (int k=0;k<8;++k) a[k] *= sc;
        } else {
            for (; i+3 < deg; i += 4){
                int s0 = es_l[start+i],   s1 = es_l[start+i+1];
                int s2 = es_l[start+i+2], s3 = es_l[start+i+3];
                float w0 = ewt_l[start+i],   w1 = ewt_l[start+i+1];
                float w2 = ewt_l[start+i+2], w3 = ewt_l[start+i+3];
                uint4 v0 = *(const uint4*)(f + (size_t)s0*DD + c*8);
                uint4 v1 = *(const uint4*)(f + (size_t)s1*DD + c*8);
                uint4 v2 = *(const uint4*)(f + (size_t)s2*DD + c*8);
                uint4 v3 = *(const uint4*)(f + (size_t)s3*DD + c*8);
                acc8(a,w0,v0); acc8(a,w1,v1); acc8(a,w2,v2); acc8(a,w3,v3);
            }
            if (i+1 < deg){
                int s0 = es_l[start+i], s1 = es_l[start+i+1];
                float w0 = ewt_l[start+i], w1 = ewt_l[start+i+1];
                uint4 v0 = *(const uint4*)(f + (size_t)s0*DD + c*8);
                uint4 v1 = *(const uint4*)(f + (size_t)s1*DD + c*8);
                acc8(a,w0,v0); acc8(a,w1,v1);
                i += 2;
            }
            if (i < deg){
                int s = es_l[start+i];
                float w = ewt_l[start+i];
                uint4 vv = *(const uint4*)(f + (size_t)s*DD + c*8);
                acc8(a,w,vv);
            }
        }
        uint4 o;
        o.x = pack2(a[0], a[1]);
        o.y = pack2(a[2], a[3]);
        o.z = pack2(a[4], a[5]);
        o.w = pack2(a[6], a[7]);
        *(uint4*)(z + (size_t)(rel*NNODES + n0 + n)*DD + c*8) = o;
    }
}

// ---- K4: w_part = sum_n w2 . tanh(W1 z_n + b1) -------------------------------
// 8 waves/block, 128 rows staged ONCE in LDS (XOR-swizzled, coalesced global
// reads), B-frags in registers; rt loop software-pipelined (LDS prefetch).
// [R11 lesson: direct-global A-frags = 16x transactions, −42 µs. LDS staging
// IS the coalescing mechanism — keep it.]
// w_part spread over 8 slots/rel.
__global__ __launch_bounds__(512, 4) void k_att(
    const unsigned short* __restrict__ z,    // bf16 [3,N,128]
    const unsigned short* __restrict__ w1,   // bf16 [512,128]
    const float* __restrict__ bias1,         // fp32 [512]
    const float* __restrict__ wv2,           // fp32 [512]
    float* __restrict__ w_part)              // fp32 [3*8] slots
{
    __shared__ uint4 sm[RT_PER_BLK*256];     // 32 KB: unit(rt,kc,m) = rt*256+kc*16+(m^kc)
    __shared__ float sred[ATT_WAVES];
    const float C2 = 2.8853900817779268f;    // 2*log2(e)

    int rel = blockIdx.x / NBLK_REL;
    int nb  = blockIdx.x % NBLK_REL;
    int trt0 = nb * RT_PER_BLK;
    int rt_count = min(RT_PER_BLK, NTILES - trt0);
    int row0 = trt0 * 16;
    const unsigned short* zrel = z + (size_t)rel*NNODES*DD;

    int lane = threadIdx.x & 63;
    int wv   = threadIdx.x >> 6;             // wave 0..7 -> cols [wv*64, wv*64+64)
    int m = lane & 15, quad = lane >> 4;

    // B fragments in registers: 4 col-tiles x 4 k-slices
    short8 bq[16];
    float ww[4], bbc[4];
    #pragma unroll
    for (int ct=0; ct<4; ++ct){
        int col = (wv*4 + ct)*16 + m;
        const short8* brow = (const short8*)(w1 + (size_t)col*DD);
        #pragma unroll
        for (int ks=0; ks<4; ++ks) bq[ct*4+ks] = brow[ks*4 + quad];
        ww[ct]  = wv2[col];
        bbc[ct] = bias1[col] * C2;
    }

    int valid_rows = rt_count * 16;
    #pragma unroll
    for (int i=0; i<4; ++i){
        int u = i*512 + threadIdx.x;         // [row(128)][kc(16)]
        int row = u >> 4, kc = u & 15;
        if (row < valid_rows){
            uint4 v = *(const uint4*)(zrel + (size_t)(row0+row)*DD + kc*8);
            int rt = row >> 4, mm = row & 15;
            sm[rt*256 + kc*16 + (mm ^ kc)] = v;
        }
    }
    __syncthreads();

    const short8* smx = (const short8*)sm;
    int o0 = (0  + quad)*16 + (m ^ (0  + quad));
    int o1 = (4  + quad)*16 + (m ^ (4  + quad));
    int o2 = (8  + quad)*16 + (m ^ (8  + quad));
    int o3 = (12 + quad)*16 + (m ^ (12 + quad));

    float s_r[4] = {0.f,0.f,0.f,0.f};
    short8 a0 = smx[o0], a1 = smx[o1], a2 = smx[o2], a3 = smx[o3];  // rt=0
    for (int rt=0; rt<rt_count; ++rt){
        short8 n0_, n1_, n2_, n3_;
        if (rt+1 < rt_count){                // prefetch next row-tile's A-frags
            int nbse = (rt+1)*256;
            n0_ = smx[nbse + o0];
            n1_ = smx[nbse + o1];
            n2_ = smx[nbse + o2];
            n3_ = smx[nbse + o3];
        } else { n0_ = a0; n1_ = a1; n2_ = a2; n3_ = a3; }
        #pragma unroll
        for (int ct=0; ct<4; ++ct){
            f32x4 acc = {0.f,0.f,0.f,0.f};
            acc = __builtin_amdgcn_mfma_f32_16x16x32_bf16(a0, bq[ct*4+0], acc, 0,0,0);
            acc = __builtin_amdgcn_mfma_f32_16x16x32_bf16(a1, bq[ct*4+1], acc, 0,0,0);
            acc = __builtin_amdgcn_mfma_f32_16x16x32_bf16(a2, bq[ct*4+2], acc, 0,0,0);
            acc = __builtin_amdgcn_mfma_f32_16x16x32_bf16(a3, bq[ct*4+3], acc, 0,0,0);
            #pragma unroll
            for (int i=0;i<4;++i){
                float e = __builtin_amdgcn_exp2f(__builtin_fmaf(acc[i], C2, bbc[ct]));
                s_r[ct] += __builtin_amdgcn_rcpf(e + 1.f);
            }
        }
        a0 = n0_; a1 = n1_; a2 = n2_; a3 = n3_;
    }
    float s_all = 0.f;
    #pragma unroll
    for (int ct=0; ct<4; ++ct)
        s_all += ww[ct]*(float)(4*rt_count) - 2.f*ww[ct]*s_r[ct];
    #pragma unroll
    for (int off=32; off; off>>=1) s_all += __shfl_xor(s_all, off);
    if (lane == 0) sred[wv] = s_all;
    __syncthreads();
    if (threadIdx.x == 0){
        float tt = 0.f;
        #pragma unroll
        for (int i=0;i<ATT_WAVES;++i) tt += sred[i];
        atomicAdd(&w_part[rel*8 + (nb & 7)], tt);    // 8 slots/rel
    }
}

// ---- K5: softmax(3) + fuse + leaky relu, fp32 out ----------------------------
__global__ __launch_bounds__(256) void k_final(
    const unsigned short* __restrict__ z0, const unsigned short* __restrict__ z1,
    const unsigned short* __restrict__ z2,
    const float* __restrict__ w_part, float* __restrict__ out)
{
    int gid = blockIdx.x*256 + threadIdx.x;      // one per 4 elements
    if (gid >= NNODES*DD/4) return;
    const float invN = 1.f / (float)NNODES;
    float w0=0.f, w1=0.f, w2=0.f;
    #pragma unroll
    for (int i=0;i<8;++i){ w0 += w_part[i]; w1 += w_part[8+i]; w2 += w_part[16+i]; }
    w0 *= invN; w1 *= invN; w2 *= invN;
    float mx = fmaxf(w0, fmaxf(w1, w2));
    const float LOG2E = 1.4426950408889634f;
    float e0 = __builtin_amdgcn_exp2f((w0-mx)*LOG2E);
    float e1 = __builtin_amdgcn_exp2f((w1-mx)*LOG2E);
    float e2 = __builtin_amdgcn_exp2f((w2-mx)*LOG2E);
    float inv = 1.f/(e0+e1+e2);
    float b0 = e0*inv, b1 = e1*inv, b2 = e2*inv;
    ushort4 g = ((const ushort4*)z0)[gid];
    ushort4 t = ((const ushort4*)z1)[gid];
    ushort4 c = ((const ushort4*)z2)[gid];
    f32x4 o;
    float gv[4] = {bf2f(g.x),bf2f(g.y),bf2f(g.z),bf2f(g.w)};
    float tv[4] = {bf2f(t.x),bf2f(t.y),bf2f(t.z),bf2f(t.w)};
    float cv[4] = {bf2f(c.x),bf2f(c.y),bf2f(c.z),bf2f(c.w)};
    #pragma unroll
    for (int i=0;i<4;++i){
        float x = b0*gv[i] + b1*tv[i] + b2*cv[i];
        o[i] = (x > 0.f) ? x : 0.2f*x;
    }
    ((f32x4*)out)[gid] = o;
}

extern "C" void kernel_launch(void* const* d_in, const int* in_sizes, int n_in,
                              void* d_out, int out_size, void* d_ws, size_t ws_size,
                              hipStream_t stream)
{
    const float* feat = (const float*)d_in[0];
    const float* W    = (const float*)d_in[1];
    const float* aw1  = (const float*)d_in[2];
    const float* ab1  = (const float*)d_in[3];
    const float* aw2  = (const float*)d_in[4];
    const float* tw   = (const float*)d_in[5];
    const int* geo_src   = (const int*)d_in[6];
    const int* geo_dst   = (const int*)d_in[7];
    const int* cat_src   = (const int*)d_in[8];
    const int* cat_dst   = (const int*)d_in[9];
    const int* trans_src = (const int*)d_in[10];
    const int* trans_dst = (const int*)d_in[11];

    // ws layout (~77 MB): w_part | bcur | w1_bf | z
    // slab/wslab (22.4 MB) live in the UPPER HALF of d_out (f_bf uses the lower
    // 25.6 MB); both are dead by the time k_final overwrites d_out.
    char* ws = (char*)d_ws;
    float* w_part = (float*)ws;                      // [64] (24 used)
    int*   bcur   = (int*)(w_part + 64);             // [1280] (GBUCK=1173, padded)
    unsigned short* w1_bf = (unsigned short*)(bcur + 1280);      // [512*128]
    unsigned short* z = w1_bf + 512*DD;              // [3N*128] geo|cat|trans

    unsigned short* f_bf = (unsigned short*)d_out;   // [N*128] bf16 (lower half)
    int2*  slab  = (int2*)((char*)d_out + (size_t)NNODES*DD*sizeof(unsigned short));
    float* wslab = (float*)(slab + (size_t)GBUCK*CAP);

    // zero w_part + bcur (contiguous)
    (void)hipMemsetAsync(w_part, 0, (64 + 1280)*sizeof(int), stream);

    k_front<<<FRONT_BLOCKS, 512, 0, stream>>>(feat, W, aw1,
                                              geo_src, geo_dst, cat_src, cat_dst,
                                              trans_src, trans_dst, tw,
                                              bcur, slab, wslab, w1_bf, f_bf);

    k_csragg<<<GBUCK, 512, 0, stream>>>(slab, wslab, bcur, f_bf, z);

    // k_att over memory-relation order (0=geo, 1=cat, 2=trans)
    k_att<<<NREL*NBLK_REL, 512, 0, stream>>>(z, w1_bf, ab1, aw2, w_part);

    unsigned short* z_geo   = z;
    unsigned short* z_cat   = z + (size_t)NNODES*DD;
    unsigned short* z_trans = z + (size_t)2*NNODES*DD;
    int dg = (NNODES*DD/4 + 255)/256;
    k_final<<<dg, 256, 0, stream>>>(z_geo, z_cat, z_trans, w_part, (float*)d_out);
}

// Round 13
// 315.350 us; speedup vs baseline: 1.1378x; 1.0133x over previous
//
#include <hip/hip_runtime.h>
#include <math.h>

#define DD 128
#define NNODES 100000
#define NEDGES 600000
#define NREL 3
#define MTOT (NREL*NNODES)
#define NTILES (NNODES/16)          // 6250 row-tiles per relation
#define RT_PER_BLK 8                // 128 rows per block
#define NBLK_REL ((NTILES + RT_PER_BLK - 1)/RT_PER_BLK)   // 782
#define ATT_WAVES 8

// bucketed CSR build (256-node buckets end-to-end)
#define BSHIFT 8
#define NBUCK ((NNODES + 255) >> BSHIFT)    // 391 buckets of 256 nodes
#define GBUCK (NREL*NBUCK)                  // 1173
#define CAP 2048                            // mean 1534, sigma 39 -> +13 sigma
#define P1_THREADS 512
#define P1_EPT 8
#define P1_EPB (P1_THREADS*P1_EPT)          // 4096 edges/block
#define P1_BLOCKS ((NREL*NEDGES + P1_EPB - 1)/P1_EPB)   // 440

// fused front-end block ranges: [part | transform | w1-cvt]
#define TR_BLOCKS ((NTILES + 7)/8)          // 782 (8 row-tiles per 512-thr block)
#define CVT_BLOCKS ((512*DD/4 + 511)/512)   // 32
#define FRONT_BLOCKS (P1_BLOCKS + TR_BLOCKS + CVT_BLOCKS)   // 1254

typedef __attribute__((ext_vector_type(8))) short short8;
typedef __attribute__((ext_vector_type(4))) float f32x4;

__device__ inline float bf2f(unsigned short u){ return __uint_as_float(((unsigned int)u)<<16); }
__device__ inline float bflo(unsigned int u){ return __uint_as_float(u<<16); }
__device__ inline float bfhi(unsigned int u){ return __uint_as_float(u & 0xffff0000u); }
__device__ inline unsigned short f2bf(float f){          // RNE fp32->bf16
    unsigned int i = __float_as_uint(f);
    unsigned int r = (i + 0x7fffu + ((i>>16)&1u)) >> 16;
    return (unsigned short)r;
}
__device__ inline unsigned int pack2(float lo, float hi){
    return (unsigned int)f2bf(lo) | ((unsigned int)f2bf(hi) << 16);
}
__device__ inline short8 cvt8(const float* __restrict__ p){  // 8 fp32 -> bf16x8
    f32x4 a = *(const f32x4*)p;
    f32x4 b = *(const f32x4*)(p+4);
    short8 t;
    t[0]=(short)f2bf(a[0]); t[1]=(short)f2bf(a[1]); t[2]=(short)f2bf(a[2]); t[3]=(short)f2bf(a[3]);
    t[4]=(short)f2bf(b[0]); t[5]=(short)f2bf(b[1]); t[6]=(short)f2bf(b[2]); t[7]=(short)f2bf(b[3]);
    return t;
}
__device__ inline void acc8(float* a, float w, uint4 v){
    a[0] += w*bflo(v.x); a[1] += w*bfhi(v.x);
    a[2] += w*bflo(v.y); a[3] += w*bfhi(v.y);
    a[4] += w*bflo(v.z); a[5] += w*bfhi(v.z);
    a[6] += w*bflo(v.w); a[7] += w*bfhi(v.w);
}

// ---- K_FRONT: fused independent front-end ------------------------------------
// Role by block range:
//   [0, P1_BLOCKS)        edge partition into (rel, 256-node-range) buckets
//                         slab entry PACKED u32: (src<<8)|local_dst
//   [.., +TR_BLOCKS)      f = feat @ W^T (W converted to bf16 in LDS once/block)
//   [.., +CVT_BLOCKS)     att_w1 fp32 -> bf16
// LDS: 32 KB buffer unioned across roles (hist | W-tile).
__global__ __launch_bounds__(512) void k_front(
    const float* __restrict__ feat, const float* __restrict__ W,
    const float* __restrict__ aw1,
    const int* __restrict__ s0, const int* __restrict__ d0,
    const int* __restrict__ s1, const int* __restrict__ d1,
    const int* __restrict__ s2, const int* __restrict__ d2,
    const float* __restrict__ tw,
    int* __restrict__ bcur, unsigned* __restrict__ slab, float* __restrict__ wslab,
    unsigned short* __restrict__ w1_bf, unsigned short* __restrict__ f_out)
{
    __shared__ char smraw[32768];
    int bid = blockIdx.x;

    if (bid < P1_BLOCKS){
        // ---------------- partition role ----------------
        int* hist = (int*)smraw;             // GBUCK=1173 ints = 4.7 KB
        for (int i=threadIdx.x; i<GBUCK; i+=512) hist[i]=0;
        __syncthreads();

        int e0 = bid * P1_EPB;
        int ss[P1_EPT], dd_[P1_EPT], gb[P1_EPT]; float wv[P1_EPT];
        #pragma unroll
        for (int j=0;j<P1_EPT;++j){
            int e = e0 + j*512 + threadIdx.x;
            gb[j] = -1;
            if (e < NREL*NEDGES){
                int rel = e / NEDGES; int i = e - rel*NEDGES;
                const int* s = (rel==0)?s0:(rel==1)?s1:s2;
                const int* d = (rel==0)?d0:(rel==1)?d1:d2;
                ss[j]=s[i]; dd_[j]=d[i];
                wv[j] = (rel==2)? tw[i] : 0.f;
                gb[j] = rel*NBUCK + (dd_[j]>>BSHIFT);
                atomicAdd(&hist[gb[j]], 1);
            }
        }
        __syncthreads();
        for (int i=threadIdx.x; i<GBUCK; i+=512){
            int c = hist[i];
            hist[i] = (c>0) ? atomicAdd(&bcur[i], c) : 0;   // count -> block base
        }
        __syncthreads();
        #pragma unroll
        for (int j=0;j<P1_EPT;++j){
            if (gb[j] >= 0){
                int off = atomicAdd(&hist[gb[j]], 1);
                slab[(size_t)gb[j]*CAP + off] =
                    ((unsigned)ss[j] << 8) | (unsigned)(dd_[j] & 255);
                if (gb[j] >= 2*NBUCK) wslab[(size_t)(gb[j]-2*NBUCK)*CAP + off] = wv[j];
            }
        }
    } else if (bid < P1_BLOCKS + TR_BLOCKS){
        // ---------------- transform role (8 row-tiles/block) ----------------
        short8* wlds = (short8*)smraw;       // bf16 [128][16 chunks], chunk^=(row&7)
        {
            int t = threadIdx.x;             // thread t: row t>>2, chunks (t&3)*4..+4
            int row = t >> 2;
            int c0  = (t & 3) * 4;
            const float* wrow = W + (size_t)row*DD;
            #pragma unroll
            for (int cc=0; cc<4; ++cc){
                int chunk = c0 + cc;
                wlds[row*16 + (chunk ^ (row & 7))] = cvt8(wrow + chunk*8);
            }
        }
        __syncthreads();

        int wid = (bid - P1_BLOCKS)*8 + (threadIdx.x>>6);
        if (wid >= NTILES) return;
        int lane = threadIdx.x & 63;
        int m = lane & 15, quad = lane >> 4;
        int n0 = wid*16;

        short8 a[4];                                   // A[m][k], k=ks*32+quad*8+j
        const float* arow = feat + (size_t)(n0+m)*DD;
        #pragma unroll
        for (int ks=0; ks<4; ++ks) a[ks] = cvt8(arow + ks*32 + quad*8);

        #pragma unroll
        for (int ct=0; ct<8; ++ct){
            f32x4 acc = {0.f,0.f,0.f,0.f};
            int brow = ct*16 + m;                      // B[k][n]=W[n][k]
            #pragma unroll
            for (int ks=0; ks<4; ++ks){
                short8 b = wlds[brow*16 + ((ks*4 + quad) ^ (brow & 7))];
                acc = __builtin_amdgcn_mfma_f32_16x16x32_bf16(a[ks], b, acc, 0,0,0);
            }
            int col = ct*16 + m;
            #pragma unroll
            for (int i=0;i<4;++i)                      // C/D: col=lane&15, row=quad*4+reg
                f_out[(size_t)(n0+quad*4+i)*DD + col] = f2bf(acc[i]);
        }
    } else {
        // ---------------- w1 conversion role ----------------
        int gid = (bid - P1_BLOCKS - TR_BLOCKS)*512 + threadIdx.x;
        if (gid < 512*DD/4){
            f32x4 v = ((const f32x4*)aw1)[gid];
            ushort4 o;
            o.x=f2bf(v[0]); o.y=f2bf(v[1]); o.z=f2bf(v[2]); o.w=f2bf(v[3]);
            ((ushort4*)w1_bf)[gid] = o;
        }
    }
}

// ---- K_CSRAGG: per-bucket CSR (fully in LDS) + aggregation -------------------
// One block per (rel, 256-node bucket). Slab entries packed u32 (src<<8|lo).
// Hist+scan+scatter build the node edge lists in LDS; agg phase: 32 groups x
// 16 lanes, 4-deep gather unroll.
__global__ __launch_bounds__(512) void k_csragg(
    const unsigned* __restrict__ slab, const float* __restrict__ wslab,
    const int* __restrict__ bcur,
    const unsigned short* __restrict__ f,   // bf16 [N,128]
    unsigned short* __restrict__ z)         // bf16 [3,N,128]
{
    __shared__ int lcnt[256];
    __shared__ int lsc[256];
    __shared__ int psum[256];
    __shared__ int es_l[CAP];
    __shared__ float ewt_l[CAP];

    int gb = blockIdx.x;
    int rel = gb / NBUCK, b = gb - rel*NBUCK;
    int n0 = b << BSHIFT;
    int nn = min(256, NNODES - n0);
    int ecount = bcur[gb];
    const unsigned* ep = slab + (size_t)gb*CAP;
    int t = threadIdx.x;
    bool wr = (rel == 2);

    if (t < 256) lcnt[t] = 0;
    __syncthreads();
    for (int i=t; i<ecount; i+=512)
        atomicAdd(&lcnt[ep[i] & 255u], 1);
    __syncthreads();
    int v = 0;
    if (t < 256){ v = lcnt[t]; psum[t] = v; }
    __syncthreads();
    for (int off=1; off<256; off<<=1){
        int x = 0;
        if (t < 256 && t >= off) x = psum[t-off];
        __syncthreads();
        if (t < 256) psum[t] += x;
        __syncthreads();
    }
    if (t < 256) lsc[t] = psum[t] - v;      // exclusive start
    __syncthreads();
    for (int i=t; i<ecount; i+=512){
        unsigned pr = ep[i];
        int pos = atomicAdd(&lsc[pr & 255u], 1);
        es_l[pos] = (int)(pr >> 8);
        if (wr) ewt_l[pos] = wslab[(size_t)b*CAP + i];
    }
    __syncthreads();                         // lsc[n] now = END offset

    int grp = t >> 4, c = t & 15;
    for (int pass=0; pass<8; ++pass){
        int n = pass*32 + grp;               // 0..255
        if (n >= nn) break;                  // monotone in pass -> safe
        int deg = lcnt[n];
        int start = lsc[n] - deg;
        float a[8] = {0,0,0,0,0,0,0,0};
        int i = 0;
        if (!wr){
            for (; i+3 < deg; i += 4){
                int s0 = es_l[start+i],   s1 = es_l[start+i+1];
                int s2 = es_l[start+i+2], s3 = es_l[start+i+3];
                uint4 v0 = *(const uint4*)(f + (size_t)s0*DD + c*8);
                uint4 v1 = *(const uint4*)(f + (size_t)s1*DD + c*8);
                uint4 v2 = *(const uint4*)(f + (size_t)s2*DD + c*8);
                uint4 v3 = *(const uint4*)(f + (size_t)s3*DD + c*8);
                acc8(a,1.f,v0); acc8(a,1.f,v1); acc8(a,1.f,v2); acc8(a,1.f,v3);
            }
            if (i+1 < deg){
                int s0 = es_l[start+i], s1 = es_l[start+i+1];
                uint4 v0 = *(const uint4*)(f + (size_t)s0*DD + c*8);
                uint4 v1 = *(const uint4*)(f + (size_t)s1*DD + c*8);
                acc8(a,1.f,v0); acc8(a,1.f,v1);
                i += 2;
            }
            if (i < deg){
                int s = es_l[start+i];
                uint4 vv = *(const uint4*)(f + (size_t)s*DD + c*8);
                acc8(a,1.f,vv);
            }
            float sc = 1.f/fmaxf((float)deg, 1.f);
            #pragma unroll
            for (int k=0;k<8;++k) a[k] *= sc;
        } else {
            for (; i+3 < deg; i += 4){
                int s0 = es_l[start+i],   s1 = es_l[start+i+1];
                int s2 = es_l[start+i+2], s3 = es_l[start+i+3];
                float w0 = ewt_l[start+i],   w1 = ewt_l[start+i+1];
                float w2 = ewt_l[start+i+2], w3 = ewt_l[start+i+3];
                uint4 v0 = *(const uint4*)(f + (size_t)s0*DD + c*8);
                uint4 v1 = *(const uint4*)(f + (size_t)s1*DD + c*8);
                uint4 v2 = *(const uint4*)(f + (size_t)s2*DD + c*8);
                uint4 v3 = *(const uint4*)(f + (size_t)s3*DD + c*8);
                acc8(a,w0,v0); acc8(a,w1,v1); acc8(a,w2,v2); acc8(a,w3,v3);
            }
            if (i+1 < deg){
                int s0 = es_l[start+i], s1 = es_l[start+i+1];
                float w0 = ewt_l[start+i], w1 = ewt_l[start+i+1];
                uint4 v0 = *(const uint4*)(f + (size_t)s0*DD + c*8);
                uint4 v1 = *(const uint4*)(f + (size_t)s1*DD + c*8);
                acc8(a,w0,v0); acc8(a,w1,v1);
                i += 2;
            }
            if (i < deg){
                int s = es_l[start+i];
                float w = ewt_l[start+i];
                uint4 vv = *(const uint4*)(f + (size_t)s*DD + c*8);
                acc8(a,w,vv);
            }
        }
        uint4 o;
        o.x = pack2(a[0], a[1]);
        o.y = pack2(a[2], a[3]);
        o.z = pack2(a[4], a[5]);
        o.w = pack2(a[6], a[7]);
        *(uint4*)(z + (size_t)(rel*NNODES + n0 + n)*DD + c*8) = o;
    }
}

// ---- K4: w_part = sum_n w2 . tanh(W1 z_n + b1) -------------------------------
// 8 waves/block, 128 rows staged ONCE in LDS (XOR-swizzled, coalesced global
// reads), B-frags in registers; rt loop software-pipelined (LDS prefetch).
// [R11 lesson: direct-global A-frags = 16x transactions, −42 µs. LDS staging
// IS the coalescing mechanism — keep it.]
__global__ __launch_bounds__(512, 4) void k_att(
    const unsigned short* __restrict__ z,    // bf16 [3,N,128]
    const unsigned short* __restrict__ w1,   // bf16 [512,128]
    const float* __restrict__ bias1,         // fp32 [512]
    const float* __restrict__ wv2,           // fp32 [512]
    float* __restrict__ w_part)              // fp32 [3*8] slots
{
    __shared__ uint4 sm[RT_PER_BLK*256];     // 32 KB: unit(rt,kc,m) = rt*256+kc*16+(m^kc)
    __shared__ float sred[ATT_WAVES];
    const float C2 = 2.8853900817779268f;    // 2*log2(e)

    int rel = blockIdx.x / NBLK_REL;
    int nb  = blockIdx.x % NBLK_REL;
    int trt0 = nb * RT_PER_BLK;
    int rt_count = min(RT_PER_BLK, NTILES - trt0);
    int row0 = trt0 * 16;
    const unsigned short* zrel = z + (size_t)rel*NNODES*DD;

    int lane = threadIdx.x & 63;
    int wv   = threadIdx.x >> 6;             // wave 0..7 -> cols [wv*64, wv*64+64)
    int m = lane & 15, quad = lane >> 4;

    // B fragments in registers: 4 col-tiles x 4 k-slices
    short8 bq[16];
    float ww[4], bbc[4];
    #pragma unroll
    for (int ct=0; ct<4; ++ct){
        int col = (wv*4 + ct)*16 + m;
        const short8* brow = (const short8*)(w1 + (size_t)col*DD);
        #pragma unroll
        for (int ks=0; ks<4; ++ks) bq[ct*4+ks] = brow[ks*4 + quad];
        ww[ct]  = wv2[col];
        bbc[ct] = bias1[col] * C2;
    }

    int valid_rows = rt_count * 16;
    #pragma unroll
    for (int i=0; i<4; ++i){
        int u = i*512 + threadIdx.x;         // [row(128)][kc(16)]
        int row = u >> 4, kc = u & 15;
        if (row < valid_rows){
            uint4 v = *(const uint4*)(zrel + (size_t)(row0+row)*DD + kc*8);
            int rt = row >> 4, mm = row & 15;
            sm[rt*256 + kc*16 + (mm ^ kc)] = v;
        }
    }
    __syncthreads();

    const short8* smx = (const short8*)sm;
    int o0 = (0  + quad)*16 + (m ^ (0  + quad));
    int o1 = (4  + quad)*16 + (m ^ (4  + quad));
    int o2 = (8  + quad)*16 + (m ^ (8  + quad));
    int o3 = (12 + quad)*16 + (m ^ (12 + quad));

    float s_r[4] = {0.f,0.f,0.f,0.f};
    short8 a0 = smx[o0], a1 = smx[o1], a2 = smx[o2], a3 = smx[o3];  // rt=0
    for (int rt=0; rt<rt_count; ++rt){
        short8 n0_, n1_, n2_, n3_;
        if (rt+1 < rt_count){                // prefetch next row-tile's A-frags
            int nbse = (rt+1)*256;
            n0_ = smx[nbse + o0];
            n1_ = smx[nbse + o1];
            n2_ = smx[nbse + o2];
            n3_ = smx[nbse + o3];
        } else { n0_ = a0; n1_ = a1; n2_ = a2; n3_ = a3; }
        #pragma unroll
        for (int ct=0; ct<4; ++ct){
            f32x4 acc = {0.f,0.f,0.f,0.f};
            acc = __builtin_amdgcn_mfma_f32_16x16x32_bf16(a0, bq[ct*4+0], acc, 0,0,0);
            acc = __builtin_amdgcn_mfma_f32_16x16x32_bf16(a1, bq[ct*4+1], acc, 0,0,0);
            acc = __builtin_amdgcn_mfma_f32_16x16x32_bf16(a2, bq[ct*4+2], acc, 0,0,0);
            acc = __builtin_amdgcn_mfma_f32_16x16x32_bf16(a3, bq[ct*4+3], acc, 0,0,0);
            #pragma unroll
            for (int i=0;i<4;++i){
                float e = __builtin_amdgcn_exp2f(__builtin_fmaf(acc[i], C2, bbc[ct]));
                s_r[ct] += __builtin_amdgcn_rcpf(e + 1.f);
            }
        }
        a0 = n0_; a1 = n1_; a2 = n2_; a3 = n3_;
    }
    float s_all = 0.f;
    #pragma unroll
    for (int ct=0; ct<4; ++ct)
        s_all += ww[ct]*(float)(4*rt_count) - 2.f*ww[ct]*s_r[ct];
    #pragma unroll
    for (int off=32; off; off>>=1) s_all += __shfl_xor(s_all, off);
    if (lane == 0) sred[wv] = s_all;
    __syncthreads();
    if (threadIdx.x == 0){
        float tt = 0.f;
        #pragma unroll
        for (int i=0;i<ATT_WAVES;++i) tt += sred[i];
        atomicAdd(&w_part[rel*8 + (nb & 7)], tt);    // 8 slots/rel
    }
}

// ---- K5: softmax(3) + fuse + leaky relu, fp32 out (8 elems/thread) -----------
__global__ __launch_bounds__(256) void k_final(
    const unsigned short* __restrict__ z0, const unsigned short* __restrict__ z1,
    const unsigned short* __restrict__ z2,
    const float* __restrict__ w_part, float* __restrict__ out)
{
    int gid = blockIdx.x*256 + threadIdx.x;      // one per 8 elements
    if (gid >= NNODES*DD/8) return;
    const float invN = 1.f / (float)NNODES;
    float w0=0.f, w1=0.f, w2=0.f;
    #pragma unroll
    for (int i=0;i<8;++i){ w0 += w_part[i]; w1 += w_part[8+i]; w2 += w_part[16+i]; }
    w0 *= invN; w1 *= invN; w2 *= invN;
    float mx = fmaxf(w0, fmaxf(w1, w2));
    const float LOG2E = 1.4426950408889634f;
    float e0 = __builtin_amdgcn_exp2f((w0-mx)*LOG2E);
    float e1 = __builtin_amdgcn_exp2f((w1-mx)*LOG2E);
    float e2 = __builtin_amdgcn_exp2f((w2-mx)*LOG2E);
    float inv = 1.f/(e0+e1+e2);
    float b0 = e0*inv, b1 = e1*inv, b2 = e2*inv;
    uint4 g = ((const uint4*)z0)[gid];           // 8 bf16
    uint4 t = ((const uint4*)z1)[gid];
    uint4 c = ((const uint4*)z2)[gid];
    float gv[8] = {bflo(g.x),bfhi(g.x),bflo(g.y),bfhi(g.y),
                   bflo(g.z),bfhi(g.z),bflo(g.w),bfhi(g.w)};
    float tv[8] = {bflo(t.x),bfhi(t.x),bflo(t.y),bfhi(t.y),
                   bflo(t.z),bfhi(t.z),bflo(t.w),bfhi(t.w)};
    float cv[8] = {bflo(c.x),bfhi(c.x),bflo(c.y),bfhi(c.y),
                   bflo(c.z),bfhi(c.z),bflo(c.w),bfhi(c.w)};
    f32x4 oA, oB;
    #pragma unroll
    for (int i=0;i<4;++i){
        float x = b0*gv[i] + b1*tv[i] + b2*cv[i];
        oA[i] = (x > 0.f) ? x : 0.2f*x;
    }
    #pragma unroll
    for (int i=0;i<4;++i){
        float x = b0*gv[4+i] + b1*tv[4+i] + b2*cv[4+i];
        oB[i] = (x > 0.f) ? x : 0.2f*x;
    }
    ((f32x4*)out)[2*gid]   = oA;
    ((f32x4*)out)[2*gid+1] = oB;
}

extern "C" void kernel_launch(void* const* d_in, const int* in_sizes, int n_in,
                              void* d_out, int out_size, void* d_ws, size_t ws_size,
                              hipStream_t stream)
{
    const float* feat = (const float*)d_in[0];
    const float* W    = (const float*)d_in[1];
    const float* aw1  = (const float*)d_in[2];
    const float* ab1  = (const float*)d_in[3];
    const float* aw2  = (const float*)d_in[4];
    const float* tw   = (const float*)d_in[5];
    const int* geo_src   = (const int*)d_in[6];
    const int* geo_dst   = (const int*)d_in[7];
    const int* cat_src   = (const int*)d_in[8];
    const int* cat_dst   = (const int*)d_in[9];
    const int* trans_src = (const int*)d_in[10];
    const int* trans_dst = (const int*)d_in[11];

    // ws layout (~77 MB): w_part | bcur | w1_bf | z
    // slab (9.6 MB, packed u32) + wslab (3.2 MB) live in the UPPER HALF of
    // d_out (f_bf uses the lower 25.6 MB); dead before k_final overwrites.
    char* ws = (char*)d_ws;
    float* w_part = (float*)ws;                      // [64] (24 used)
    int*   bcur   = (int*)(w_part + 64);             // [1280] (GBUCK=1173, padded)
    unsigned short* w1_bf = (unsigned short*)(bcur + 1280);      // [512*128]
    unsigned short* z = w1_bf + 512*DD;              // [3N*128] geo|cat|trans

    unsigned short* f_bf = (unsigned short*)d_out;   // [N*128] bf16 (lower half)
    unsigned* slab = (unsigned*)((char*)d_out + (size_t)NNODES*DD*sizeof(unsigned short));
    float* wslab = (float*)(slab + (size_t)GBUCK*CAP);

    // zero w_part + bcur (contiguous)
    (void)hipMemsetAsync(w_part, 0, (64 + 1280)*sizeof(int), stream);

    k_front<<<FRONT_BLOCKS, 512, 0, stream>>>(feat, W, aw1,
                                              geo_src, geo_dst, cat_src, cat_dst,
                                              trans_src, trans_dst, tw,
                                              bcur, slab, wslab, w1_bf, f_bf);

    k_csragg<<<GBUCK, 512, 0, stream>>>(slab, wslab, bcur, f_bf, z);

    // k_att over memory-relation order (0=geo, 1=cat, 2=trans)
    k_att<<<NREL*NBLK_REL, 512, 0, stream>>>(z, w1_bf, ab1, aw2, w_part);

    unsigned short* z_geo   = z;
    unsigned short* z_cat   = z + (size_t)NNODES*DD;
    unsigned short* z_trans = z + (size_t)2*NNODES*DD;
    int dg = (NNODES*DD/8 + 255)/256;
    k_final<<<dg, 256, 0, stream>>>(z_geo, z_cat, z_trans, w_part, (float*)d_out);
}